// Round 5
// baseline (335.472 us; speedup 1.0000x reference)
//
#include <hip/hip_runtime.h>

#define NODE_DIM 128
#define NUM_IRREPS 224
#define SPH_DIM 480
#define HIDDEN 576   // NODE_DIM + 2*NUM_IRREPS
#define NUM_BASIS 20
#define N_NODES 10000
#define N_EDGES 160000
#define NPB 8        // nodes per block in node MLP

// ---------------- init: d_out = concat(x_scalar, x_spherical); zero counts ----------------
__global__ void init_out(const float* __restrict__ xs,
                         const float* __restrict__ xsp,
                         float* __restrict__ out,
                         int* __restrict__ counts) {
    const int stride = gridDim.x * blockDim.x;
    const int t0 = blockIdx.x * blockDim.x + threadIdx.x;
    for (int i = t0; i < N_NODES * NODE_DIM; i += stride) out[i] = xs[i];
    float* o2 = out + (size_t)N_NODES * NODE_DIM;
    for (int i = t0; i < N_NODES * SPH_DIM; i += stride) o2[i] = xsp[i];
    for (int i = t0; i < N_NODES; i += stride) counts[i] = 0;
}

// ---------------- node MLP: scalar_out = silu(x@W1+b1)@W2+b2 ----------------
__global__ __launch_bounds__(128) void node_mlp(
    const float* __restrict__ x,
    const float* __restrict__ W1, const float* __restrict__ b1,
    const float* __restrict__ W2, const float* __restrict__ b2,
    float* __restrict__ so) {
    __shared__ float xs[NPB][NODE_DIM];
    __shared__ float hs[NPB][NODE_DIM];
    const int tid = threadIdx.x;
    const int n0 = blockIdx.x * NPB;

    #pragma unroll
    for (int n = 0; n < NPB; ++n) {
        int node = n0 + n;
        xs[n][tid] = (node < N_NODES) ? x[(size_t)node * NODE_DIM + tid] : 0.f;
    }
    __syncthreads();

    float acc[NPB];
    #pragma unroll
    for (int n = 0; n < NPB; ++n) acc[n] = b1[tid];
    for (int k = 0; k < NODE_DIM; ++k) {
        float w = W1[k * NODE_DIM + tid];
        #pragma unroll
        for (int n = 0; n < NPB; ++n) acc[n] = fmaf(xs[n][k], w, acc[n]);
    }
    #pragma unroll
    for (int n = 0; n < NPB; ++n) {
        float v = acc[n];
        hs[n][tid] = v / (1.f + __expf(-v));
    }
    __syncthreads();

    for (int j = tid; j < HIDDEN; j += 128) {
        float a2[NPB];
        #pragma unroll
        for (int n = 0; n < NPB; ++n) a2[n] = b2[j];
        for (int k = 0; k < NODE_DIM; ++k) {
            float w = W2[k * HIDDEN + j];
            #pragma unroll
            for (int n = 0; n < NPB; ++n) a2[n] = fmaf(hs[n][k], w, a2[n]);
        }
        #pragma unroll
        for (int n = 0; n < NPB; ++n) {
            int node = n0 + n;
            if (node < N_NODES) so[(size_t)node * HIDDEN + j] = a2[n];
        }
    }
}

// ---------------- CSR build: histogram / scan / scatter ----------------
__global__ __launch_bounds__(256) void hist_kernel(const int* __restrict__ eidx,
                                                   int* __restrict__ counts) {
    int i = blockIdx.x * blockDim.x + threadIdx.x;
    if (i < N_EDGES) atomicAdd(&counts[eidx[i]], 1);   // bucket by src
}

__global__ __launch_bounds__(1024) void scan_kernel(const int* __restrict__ counts,
                                                    int* __restrict__ offsets,
                                                    int* __restrict__ cursor) {
    __shared__ int wsum[16];
    const int tid = threadIdx.x;
    int vals[10];
    int run = 0;
    #pragma unroll
    for (int i = 0; i < 10; ++i) {
        int idx = tid * 10 + i;
        int c = (idx < N_NODES) ? counts[idx] : 0;
        vals[i] = run;
        run += c;
    }
    const int lane = tid & 63, w = tid >> 6;
    int inc = run;
    #pragma unroll
    for (int off = 1; off < 64; off <<= 1) {
        int v = __shfl_up(inc, off);
        if (lane >= off) inc += v;
    }
    if (lane == 63) wsum[w] = inc;
    __syncthreads();
    if (w == 0) {
        int v = (lane < 16) ? wsum[lane] : 0;
        #pragma unroll
        for (int off = 1; off < 16; off <<= 1) {
            int u = __shfl_up(v, off);
            if (lane >= off) v += u;
        }
        if (lane < 16) wsum[lane] = v;
    }
    __syncthreads();
    const int wbase = (w > 0) ? wsum[w - 1] : 0;
    const int base = wbase + inc - run;   // exclusive prefix for this thread
    #pragma unroll
    for (int i = 0; i < 10; ++i) {
        int idx = tid * 10 + i;
        if (idx < N_NODES) {
            int v = base + vals[i];
            offsets[idx] = v;
            cursor[idx] = v;
        }
    }
    if (tid == 1023) offsets[N_NODES] = wbase + inc;
}

__global__ __launch_bounds__(256) void scatter_kernel(const int* __restrict__ eidx,
                                                      int* __restrict__ cursor,
                                                      int* __restrict__ edge_order) {
    int i = blockIdx.x * blockDim.x + threadIdx.x;
    if (i < N_EDGES) {
        int s = eidx[i];
        int pos = atomicAdd(&cursor[s], 1);
        edge_order[pos] = i;
    }
}

// ---------------- node gather: fully software-pipelined, no LDS, no barriers ----------------
// Roles: t<224 -> irrep r=t; t in [224,256) -> dup of irrep t-32 tail elements.
// Per thread: Wr columns in registers; payload (rbf row + so/xsp/rsh gathers)
// prefetched one edge ahead; edge metadata prefetched three ahead.
#define DOT20(a, WREG) do { \
    a = fmaf(q0.x, WREG[0], a);  a = fmaf(q0.y, WREG[1], a);  a = fmaf(q0.z, WREG[2], a);  a = fmaf(q0.w, WREG[3], a); \
    a = fmaf(q1.x, WREG[4], a);  a = fmaf(q1.y, WREG[5], a);  a = fmaf(q1.z, WREG[6], a);  a = fmaf(q1.w, WREG[7], a); \
    a = fmaf(q2.x, WREG[8], a);  a = fmaf(q2.y, WREG[9], a);  a = fmaf(q2.z, WREG[10], a); a = fmaf(q2.w, WREG[11], a); \
    a = fmaf(q3.x, WREG[12], a); a = fmaf(q3.y, WREG[13], a); a = fmaf(q3.z, WREG[14], a); a = fmaf(q3.w, WREG[15], a); \
    a = fmaf(q4.x, WREG[16], a); a = fmaf(q4.y, WREG[17], a); a = fmaf(q4.z, WREG[18], a); a = fmaf(q4.w, WREG[19], a); \
} while (0)

#define LOAD_PAYLOAD() do { \
    const float4* rq = (const float4*)(rbf + (size_t)eC * NUM_BASIS); \
    q0 = rq[0]; q1 = rq[1]; q2 = rq[2]; q3 = rq[3]; q4 = rq[4]; \
    const float* sod = so + (size_t)dC * HIDDEN; \
    s0 = sod[j0]; s1 = sod[j1]; \
    if (has2) s2 = sod[j2]; \
    const float* xd = xsp + (size_t)dC * SPH_DIM + d0; \
    const float* rd = rsh + (size_t)eC * SPH_DIM + d0; \
    x0 = xd[0]; r0 = rd[0]; \
    if (nd > 1) { x1 = xd[1]; r1 = rd[1]; } \
    if (nd > 2) { x2 = xd[2]; r2 = rd[2]; } \
} while (0)

__global__ __launch_bounds__(256, 4) void node_gather(
    const float* __restrict__ xsp,
    const float* __restrict__ rbf, const float* __restrict__ fcut,
    const float* __restrict__ rsh, const int* __restrict__ eidx,
    const float* __restrict__ Wr, const float* __restrict__ br,
    const float* __restrict__ so,
    const int* __restrict__ offsets, const int* __restrict__ edge_order,
    float* __restrict__ out_scalar, float* __restrict__ out_sph)
{
    const int t = threadIdx.x;
    const int n = blockIdx.x;
    const bool dup  = (t >= 224);
    const int  r    = dup ? (t - 32) : t;       // irrep index in [0,224)
    const int  j0   = r;                        // gate_state column
    const int  j1   = NUM_IRREPS + r;           // gate_edge column
    const bool has2 = (t < 128);                // owns a message_scalar column
    const int  j2   = 2 * NUM_IRREPS + (t & 127);

    int nd, d0;
    if (t < 128)      { nd = 1; d0 = t; }
    else if (t < 192) { nd = 3; d0 = 128 + (t - 128) * 3; }
    else if (t < 224) { nd = 3; d0 = 320 + (t - 192) * 5; }
    else              { nd = 2; d0 = 320 + (t - 224) * 5 + 3; }

    float wr0[NUM_BASIS], wr1[NUM_BASIS], wr2[NUM_BASIS];
    #pragma unroll
    for (int k = 0; k < NUM_BASIS; ++k) {
        wr0[k] = Wr[k * HIDDEN + j0];
        wr1[k] = Wr[k * HIDDEN + j1];
        wr2[k] = has2 ? Wr[k * HIDDEN + j2] : 0.f;
    }
    const float br0 = br[j0], br1 = br[j1], br2 = has2 ? br[j2] : 0.f;

    const int beg  = offsets[n];
    const int end_ = offsets[n + 1];

    float accS = 0.f, accD0 = 0.f, accD1 = 0.f, accD2 = 0.f;

    if (beg < end_) {
        const int last = end_ - 1;
        const int i1 = min(beg + 1, last);
        const int i2 = min(beg + 2, last);
        const int i3 = min(beg + 3, last);
        // meta pipeline: cur / +1 / +2 full, +3 id-only
        int   eC = edge_order[beg];
        int   e1 = edge_order[i1];
        int   e2 = edge_order[i2];
        int   e3 = edge_order[i3];
        int   dC = eidx[N_EDGES + eC]; float fC = fcut[eC];
        int   d1 = eidx[N_EDGES + e1]; float f1 = fcut[e1];
        int   d2 = eidx[N_EDGES + e2]; float f2 = fcut[e2];

        float4 q0, q1, q2, q3, q4;
        float  s0, s1, s2 = 0.f, x0, x1 = 0.f, x2 = 0.f, r0, r1 = 0.f, r2 = 0.f;
        LOAD_PAYLOAD();

        for (int idx = beg; idx <= last; ++idx) {
            // ---- compute current edge (payload resident in regs) ----
            float a0 = br0, a1 = br1, a2 = br2;
            DOT20(a0, wr0);
            DOT20(a1, wr1);
            if (has2) { DOT20(a2, wr2); }
            const float fo0 = a0 * fC * s0;
            const float fo1 = a1 * fC * s1;
            if (has2) accS = fmaf(a2 * fC, s2, accS);
            accD0 = fmaf(x0, fo0, fmaf(r0, fo1, accD0));
            if (nd > 1) accD1 = fmaf(x1, fo0, fmaf(r1, fo1, accD1));
            if (nd > 2) accD2 = fmaf(x2, fo0, fmaf(r2, fo1, accD2));

            // ---- rotate meta ----
            eC = e1; dC = d1; fC = f1;
            e1 = e2; d1 = d2; f1 = f2;
            // ---- issue payload for next edge (idx+1) ----
            LOAD_PAYLOAD();
            // ---- complete meta for idx+3; fetch id for idx+4 ----
            e2 = e3;
            d2 = eidx[N_EDGES + e3]; f2 = fcut[e3];
            e3 = edge_order[min(idx + 4, last)];
        }
    }

    if (t < 128) out_scalar[(size_t)n * NODE_DIM + t] += accS;
    float* od = out_sph + (size_t)n * SPH_DIM + d0;
    od[0] += accD0;
    if (nd > 1) od[1] += accD1;
    if (nd > 2) od[2] += accD2;
}

extern "C" void kernel_launch(void* const* d_in, const int* in_sizes, int n_in,
                              void* d_out, int out_size, void* d_ws, size_t ws_size,
                              hipStream_t stream) {
    const float* x_scalar    = (const float*)d_in[0];
    const float* x_spherical = (const float*)d_in[1];
    const float* rbf         = (const float*)d_in[2];
    const float* fcut        = (const float*)d_in[3];
    const float* rsh         = (const float*)d_in[4];
    const int*   eidx        = (const int*)d_in[5];
    const float* W1          = (const float*)d_in[6];
    const float* b1          = (const float*)d_in[7];
    const float* W2          = (const float*)d_in[8];
    const float* b2          = (const float*)d_in[9];
    const float* Wr          = (const float*)d_in[10];
    const float* br          = (const float*)d_in[11];

    float* out        = (float*)d_out;
    float* out_scalar = out;                                   // (N_NODES, 128)
    float* out_sph    = out + (size_t)N_NODES * NODE_DIM;      // (N_NODES, 480)

    // workspace layout
    float* scalar_out = (float*)d_ws;                          // 10000*576 floats
    int*   counts     = (int*)(scalar_out + (size_t)N_NODES * HIDDEN);   // 10000
    int*   offsets    = counts + N_NODES;                      // 10001
    int*   cursor     = offsets + N_NODES + 1;                 // 10000
    int*   edge_order = cursor + N_NODES;                      // 160000

    init_out<<<2048, 256, 0, stream>>>(x_scalar, x_spherical, out, counts);
    hist_kernel<<<(N_EDGES + 255) / 256, 256, 0, stream>>>(eidx, counts);
    scan_kernel<<<1, 1024, 0, stream>>>(counts, offsets, cursor);
    scatter_kernel<<<(N_EDGES + 255) / 256, 256, 0, stream>>>(eidx, cursor, edge_order);
    node_mlp<<<(N_NODES + NPB - 1) / NPB, 128, 0, stream>>>(x_scalar, W1, b1, W2, b2, scalar_out);
    node_gather<<<N_NODES, 256, 0, stream>>>(x_spherical, rbf, fcut, rsh, eidx,
                                             Wr, br, scalar_out, offsets, edge_order,
                                             out_scalar, out_sph);
}

// Round 6
// 308.811 us; speedup vs baseline: 1.0863x; 1.0863x over previous
//
#include <hip/hip_runtime.h>

#define NODE_DIM 128
#define NUM_IRREPS 224
#define SPH_DIM 480
#define HIDDEN 576   // NODE_DIM + 2*NUM_IRREPS
#define NUM_BASIS 20
#define N_NODES 10000
#define N_EDGES 160000
#define NPB 4        // nodes per block in node MLP

// ---------------- init: d_out = concat(x_scalar, x_spherical); zero counts ----------------
__global__ void init_out(const float* __restrict__ xs,
                         const float* __restrict__ xsp,
                         float* __restrict__ out,
                         int* __restrict__ counts) {
    const int stride = gridDim.x * blockDim.x;
    const int t0 = blockIdx.x * blockDim.x + threadIdx.x;
    for (int i = t0; i < N_NODES * NODE_DIM; i += stride) out[i] = xs[i];
    float* o2 = out + (size_t)N_NODES * NODE_DIM;
    for (int i = t0; i < N_NODES * SPH_DIM; i += stride) o2[i] = xsp[i];
    for (int i = t0; i < N_NODES; i += stride) counts[i] = 0;
}

// ---------------- node MLP: scalar_out = silu(x@W1+b1)@W2+b2 ----------------
__global__ __launch_bounds__(128) void node_mlp(
    const float* __restrict__ x,
    const float* __restrict__ W1, const float* __restrict__ b1,
    const float* __restrict__ W2, const float* __restrict__ b2,
    float* __restrict__ so) {
    __shared__ float xs[NPB][NODE_DIM];
    __shared__ float hs[NPB][NODE_DIM];
    const int tid = threadIdx.x;
    const int n0 = blockIdx.x * NPB;

    #pragma unroll
    for (int n = 0; n < NPB; ++n) {
        int node = n0 + n;
        xs[n][tid] = (node < N_NODES) ? x[(size_t)node * NODE_DIM + tid] : 0.f;
    }
    __syncthreads();

    float acc[NPB];
    #pragma unroll
    for (int n = 0; n < NPB; ++n) acc[n] = b1[tid];
    for (int k = 0; k < NODE_DIM; ++k) {
        float w = W1[k * NODE_DIM + tid];
        #pragma unroll
        for (int n = 0; n < NPB; ++n) acc[n] = fmaf(xs[n][k], w, acc[n]);
    }
    #pragma unroll
    for (int n = 0; n < NPB; ++n) {
        float v = acc[n];
        hs[n][tid] = v / (1.f + __expf(-v));
    }
    __syncthreads();

    for (int j = tid; j < HIDDEN; j += 128) {
        float a2[NPB];
        #pragma unroll
        for (int n = 0; n < NPB; ++n) a2[n] = b2[j];
        for (int k = 0; k < NODE_DIM; ++k) {
            float w = W2[k * HIDDEN + j];
            #pragma unroll
            for (int n = 0; n < NPB; ++n) a2[n] = fmaf(hs[n][k], w, a2[n]);
        }
        #pragma unroll
        for (int n = 0; n < NPB; ++n) {
            int node = n0 + n;
            if (node < N_NODES) so[(size_t)node * HIDDEN + j] = a2[n];
        }
    }
}

// ---------------- CSR build: histogram / scan / scatter ----------------
__global__ __launch_bounds__(256) void hist_kernel(const int* __restrict__ eidx,
                                                   int* __restrict__ counts) {
    int i = blockIdx.x * blockDim.x + threadIdx.x;
    if (i < N_EDGES) atomicAdd(&counts[eidx[i]], 1);   // bucket by src
}

__global__ __launch_bounds__(1024) void scan_kernel(const int* __restrict__ counts,
                                                    int* __restrict__ offsets,
                                                    int* __restrict__ cursor) {
    __shared__ int wsum[16];
    const int tid = threadIdx.x;
    int vals[10];
    int run = 0;
    #pragma unroll
    for (int i = 0; i < 10; ++i) {
        int idx = tid * 10 + i;
        int c = (idx < N_NODES) ? counts[idx] : 0;
        vals[i] = run;
        run += c;
    }
    const int lane = tid & 63, w = tid >> 6;
    int inc = run;
    #pragma unroll
    for (int off = 1; off < 64; off <<= 1) {
        int v = __shfl_up(inc, off);
        if (lane >= off) inc += v;
    }
    if (lane == 63) wsum[w] = inc;
    __syncthreads();
    if (w == 0) {
        int v = (lane < 16) ? wsum[lane] : 0;
        #pragma unroll
        for (int off = 1; off < 16; off <<= 1) {
            int u = __shfl_up(v, off);
            if (lane >= off) v += u;
        }
        if (lane < 16) wsum[lane] = v;
    }
    __syncthreads();
    const int wbase = (w > 0) ? wsum[w - 1] : 0;
    const int base = wbase + inc - run;   // exclusive prefix for this thread
    #pragma unroll
    for (int i = 0; i < 10; ++i) {
        int idx = tid * 10 + i;
        if (idx < N_NODES) {
            int v = base + vals[i];
            offsets[idx] = v;
            cursor[idx] = v;
        }
    }
    if (tid == 1023) offsets[N_NODES] = wbase + inc;
}

__global__ __launch_bounds__(256) void scatter_kernel(const int* __restrict__ eidx,
                                                      int* __restrict__ cursor,
                                                      int* __restrict__ edge_order) {
    int i = blockIdx.x * blockDim.x + threadIdx.x;
    if (i < N_EDGES) {
        int s = eidx[i];
        int pos = atomicAdd(&cursor[s], 1);
        edge_order[pos] = i;
    }
}

// ---------------- node gather: 320 threads, 2 filter-columns/thread, 2-deep pipeline ----------------
// Roles: t<224: irrep r=t (cols r, 224+r; 1-3 sph elems)
//        224<=t<256: dup tail of irrep r=t-32 (same cols; last 2 of 5 sph elems)
//        256<=t<320: scalar cols 448+2*(t-256), +1 (no sph)
#define PIN20(W) asm volatile("" : \
 "+v"(W[0]),"+v"(W[1]),"+v"(W[2]),"+v"(W[3]),"+v"(W[4]), \
 "+v"(W[5]),"+v"(W[6]),"+v"(W[7]),"+v"(W[8]),"+v"(W[9]), \
 "+v"(W[10]),"+v"(W[11]),"+v"(W[12]),"+v"(W[13]),"+v"(W[14]), \
 "+v"(W[15]),"+v"(W[16]),"+v"(W[17]),"+v"(W[18]),"+v"(W[19]))

#define DOT20(a, W, Q0,Q1,Q2,Q3,Q4) do { \
    a = fmaf(Q0.x, W[0], a);  a = fmaf(Q0.y, W[1], a);  a = fmaf(Q0.z, W[2], a);  a = fmaf(Q0.w, W[3], a); \
    a = fmaf(Q1.x, W[4], a);  a = fmaf(Q1.y, W[5], a);  a = fmaf(Q1.z, W[6], a);  a = fmaf(Q1.w, W[7], a); \
    a = fmaf(Q2.x, W[8], a);  a = fmaf(Q2.y, W[9], a);  a = fmaf(Q2.z, W[10], a); a = fmaf(Q2.w, W[11], a); \
    a = fmaf(Q3.x, W[12], a); a = fmaf(Q3.y, W[13], a); a = fmaf(Q3.z, W[14], a); a = fmaf(Q3.w, W[15], a); \
    a = fmaf(Q4.x, W[16], a); a = fmaf(Q4.y, W[17], a); a = fmaf(Q4.z, W[18], a); a = fmaf(Q4.w, W[19], a); \
} while (0)

#define LOADP(Q0,Q1,Q2,Q3,Q4, S0,S1, X0,X1,X2, R0,R1,R2, E, D) do { \
    const float4* rq = (const float4*)(rbf + (size_t)(E) * NUM_BASIS); \
    Q0 = rq[0]; Q1 = rq[1]; Q2 = rq[2]; Q3 = rq[3]; Q4 = rq[4]; \
    const float* sod = so + (size_t)(D) * HIDDEN; \
    S0 = sod[c0]; S1 = sod[c1]; \
    if (sphMode) { \
        const float* xd = xsp + (size_t)(D) * SPH_DIM + db; \
        const float* rd = rsh + (size_t)(E) * SPH_DIM + db; \
        X0 = xd[0]; R0 = rd[0]; \
        if (nd > 1) { X1 = xd[1]; R1 = rd[1]; } \
        if (nd > 2) { X2 = xd[2]; R2 = rd[2]; } \
    } \
} while (0)

#define COMPUTE(Q0,Q1,Q2,Q3,Q4, S0,S1, X0,X1,X2, R0,R1,R2, FC) do { \
    float a0 = bc0, a1 = bc1; \
    DOT20(a0, w0, Q0,Q1,Q2,Q3,Q4); \
    DOT20(a1, w1, Q0,Q1,Q2,Q3,Q4); \
    if (sphMode) { \
        const float fo0 = a0 * (FC) * S0; \
        const float fo1 = a1 * (FC) * S1; \
        accD0 = fmaf(X0, fo0, fmaf(R0, fo1, accD0)); \
        if (nd > 1) accD1 = fmaf(X1, fo0, fmaf(R1, fo1, accD1)); \
        if (nd > 2) accD2 = fmaf(X2, fo0, fmaf(R2, fo1, accD2)); \
    } else { \
        accA = fmaf(a0 * (FC), S0, accA); \
        accB = fmaf(a1 * (FC), S1, accB); \
    } \
} while (0)

__global__ __launch_bounds__(320, 3) void node_gather(
    const float* __restrict__ xsp,
    const float* __restrict__ rbf, const float* __restrict__ fcut,
    const float* __restrict__ rsh, const int* __restrict__ eidx,
    const float* __restrict__ Wr, const float* __restrict__ br,
    const float* __restrict__ so,
    const int* __restrict__ offsets, const int* __restrict__ edge_order,
    float* __restrict__ out_scalar, float* __restrict__ out_sph)
{
    const int t = threadIdx.x;
    const int n = blockIdx.x;
    const bool sphMode = (t < 256);   // waves 0-3 sph, wave 4 scalar (wave-uniform)

    int c0, c1;
    if (t < 224)      { c0 = t;                  c1 = NUM_IRREPS + t; }
    else if (t < 256) { c0 = t - 32;             c1 = NUM_IRREPS + (t - 32); }
    else              { c0 = 448 + 2 * (t - 256); c1 = c0 + 1; }

    int nd, db;
    if (t < 128)      { nd = 1; db = t; }
    else if (t < 192) { nd = 3; db = 128 + (t - 128) * 3; }
    else if (t < 224) { nd = 3; db = 320 + (t - 192) * 5; }
    else if (t < 256) { nd = 2; db = 320 + (t - 224) * 5 + 3; }
    else              { nd = 0; db = 0; }

    float w0[NUM_BASIS], w1[NUM_BASIS];
    #pragma unroll
    for (int k = 0; k < NUM_BASIS; ++k) {
        w0[k] = Wr[k * HIDDEN + c0];
        w1[k] = Wr[k * HIDDEN + c1];
    }
    const float bc0 = br[c0], bc1 = br[c1];

    const int beg  = offsets[n];
    const int end_ = offsets[n + 1];

    float accD0 = 0.f, accD1 = 0.f, accD2 = 0.f, accA = 0.f, accB = 0.f;

    if (beg < end_) {
        const int last = end_ - 1;
        // meta queues: edge ids 6-deep, dst/fcut 4-deep (all clamped to last)
        int e0 = edge_order[beg];
        int e1 = edge_order[min(beg + 1, last)];
        int e2 = edge_order[min(beg + 2, last)];
        int e3 = edge_order[min(beg + 3, last)];
        int e4 = edge_order[min(beg + 4, last)];
        int e5 = edge_order[min(beg + 5, last)];
        int d0q = eidx[N_EDGES + e0]; float f0 = fcut[e0];
        int d1q = eidx[N_EDGES + e1]; float f1 = fcut[e1];
        int d2q = eidx[N_EDGES + e2]; float f2 = fcut[e2];
        int d3q = eidx[N_EDGES + e3]; float f3 = fcut[e3];

        float4 qA0, qA1, qA2, qA3, qA4, qB0, qB1, qB2, qB3, qB4;
        float sA0, sA1, xA0 = 0.f, xA1 = 0.f, xA2 = 0.f, rA0 = 0.f, rA1 = 0.f, rA2 = 0.f;
        float sB0, sB1, xB0 = 0.f, xB1 = 0.f, xB2 = 0.f, rB0 = 0.f, rB1 = 0.f, rB2 = 0.f;
        LOADP(qA0,qA1,qA2,qA3,qA4, sA0,sA1, xA0,xA1,xA2, rA0,rA1,rA2, e0, d0q);
        LOADP(qB0,qB1,qB2,qB3,qB4, sB0,sB1, xB0,xB1,xB2, rB0,rB1,rB2, e1, d1q);

        for (int idx = beg; idx <= last; idx += 2) {
            PIN20(w0); PIN20(w1);
            // even edge (idx): payload A resident
            COMPUTE(qA0,qA1,qA2,qA3,qA4, sA0,sA1, xA0,xA1,xA2, rA0,rA1,rA2, f0);
            LOADP(qA0,qA1,qA2,qA3,qA4, sA0,sA1, xA0,xA1,xA2, rA0,rA1,rA2, e2, d2q);  // idx+2
            int   nd4 = eidx[N_EDGES + e4]; float nf4 = fcut[e4];                    // meta idx+4
            int   ne6 = edge_order[min(idx + 6, last)];
            // odd edge (idx+1)
            if (idx + 1 <= last) {
                COMPUTE(qB0,qB1,qB2,qB3,qB4, sB0,sB1, xB0,xB1,xB2, rB0,rB1,rB2, f1);
            }
            LOADP(qB0,qB1,qB2,qB3,qB4, sB0,sB1, xB0,xB1,xB2, rB0,rB1,rB2, e3, d3q);  // idx+3
            int   nd5 = eidx[N_EDGES + e5]; float nf5 = fcut[e5];                    // meta idx+5
            int   ne7 = edge_order[min(idx + 7, last)];
            // rotate queues by 2
            e0 = e2; e1 = e3; e2 = e4; e3 = e5; e4 = ne6; e5 = ne7;
            d0q = d2q; d1q = d3q; d2q = nd4; d3q = nd5;
            f0 = f2; f1 = f3; f2 = nf4; f3 = nf5;
        }
    }

    if (sphMode) {
        float* od = out_sph + (size_t)n * SPH_DIM + db;
        od[0] += accD0;
        if (nd > 1) od[1] += accD1;
        if (nd > 2) od[2] += accD2;
    } else {
        float* osr = out_scalar + (size_t)n * NODE_DIM + 2 * (t - 256);
        osr[0] += accA;
        osr[1] += accB;
    }
}

extern "C" void kernel_launch(void* const* d_in, const int* in_sizes, int n_in,
                              void* d_out, int out_size, void* d_ws, size_t ws_size,
                              hipStream_t stream) {
    const float* x_scalar    = (const float*)d_in[0];
    const float* x_spherical = (const float*)d_in[1];
    const float* rbf         = (const float*)d_in[2];
    const float* fcut        = (const float*)d_in[3];
    const float* rsh         = (const float*)d_in[4];
    const int*   eidx        = (const int*)d_in[5];
    const float* W1          = (const float*)d_in[6];
    const float* b1          = (const float*)d_in[7];
    const float* W2          = (const float*)d_in[8];
    const float* b2          = (const float*)d_in[9];
    const float* Wr          = (const float*)d_in[10];
    const float* br          = (const float*)d_in[11];

    float* out        = (float*)d_out;
    float* out_scalar = out;                                   // (N_NODES, 128)
    float* out_sph    = out + (size_t)N_NODES * NODE_DIM;      // (N_NODES, 480)

    // workspace layout
    float* scalar_out = (float*)d_ws;                          // 10000*576 floats
    int*   counts     = (int*)(scalar_out + (size_t)N_NODES * HIDDEN);   // 10000
    int*   offsets    = counts + N_NODES;                      // 10001
    int*   cursor     = offsets + N_NODES + 1;                 // 10000
    int*   edge_order = cursor + N_NODES;                      // 160000

    init_out<<<2048, 256, 0, stream>>>(x_scalar, x_spherical, out, counts);
    hist_kernel<<<(N_EDGES + 255) / 256, 256, 0, stream>>>(eidx, counts);
    scan_kernel<<<1, 1024, 0, stream>>>(counts, offsets, cursor);
    scatter_kernel<<<(N_EDGES + 255) / 256, 256, 0, stream>>>(eidx, cursor, edge_order);
    node_mlp<<<(N_NODES + NPB - 1) / NPB, 128, 0, stream>>>(x_scalar, W1, b1, W2, b2, scalar_out);
    node_gather<<<N_NODES, 320, 0, stream>>>(x_spherical, rbf, fcut, rsh, eidx,
                                             Wr, br, scalar_out, offsets, edge_order,
                                             out_scalar, out_sph);
}